// Round 2
// baseline (14146.062 us; speedup 1.0000x reference)
//
#include <hip/hip_runtime.h>
#include <stdint.h>

typedef float   f32x4 __attribute__((ext_vector_type(4)));
typedef float   f32x2 __attribute__((ext_vector_type(2)));
typedef int     i32x4 __attribute__((ext_vector_type(4)));
typedef int     i32x2 __attribute__((ext_vector_type(2)));
typedef __bf16  bf16x8 __attribute__((ext_vector_type(8)));

#define DEV __device__ __forceinline__

// ---------- helpers ----------
DEV uint16_t f2bf(float f){                       // RNE f32->bf16
  uint32_t u = __float_as_uint(f);
  u += 0x7fffu + ((u >> 16) & 1u);
  return (uint16_t)(u >> 16);
}
DEV uint32_t pkbf(float lo, float hi){            // pack 2 bf16 into u32
  uint32_t r;
  asm("v_cvt_pk_bf16_f32 %0, %1, %2" : "=v"(r) : "v"(lo), "v"(hi));
  return r;
}
// byte offset inside a [row][128 bf16] tile with XOR-16B bank swizzle
DEV uint32_t aoff(uint32_t row, uint32_t q){ return (row << 8) + (q ^ ((row & 7u) << 4)); }

DEV f32x4 MFMA(bf16x8 a, bf16x8 b, f32x4 c){
  return __builtin_amdgcn_mfma_f32_16x16x32_bf16(a, b, c, 0, 0, 0);
}

// ---------- two-level grid barrier (monotonic epochs; bar zeroed per call) ----------
// layout (u32 indices): group counters at g*32 (8 groups, 128B apart), root at 256, go-word at 288
DEV void gridbar(uint32_t* bar, uint32_t ep, int grp){
  __syncthreads();
  if (threadIdx.x == 0){
    __threadfence();
    uint32_t a = __hip_atomic_fetch_add(bar + grp*32, 1u, __ATOMIC_ACQ_REL, __HIP_MEMORY_SCOPE_AGENT);
    if (a == 32u*ep - 1u){
      uint32_t r = __hip_atomic_fetch_add(bar + 256, 1u, __ATOMIC_ACQ_REL, __HIP_MEMORY_SCOPE_AGENT);
      if (r == 8u*ep - 1u)
        __hip_atomic_store(bar + 288, ep, __ATOMIC_RELEASE, __HIP_MEMORY_SCOPE_AGENT);
    }
    int spins = 0;
    while (__hip_atomic_load(bar + 288, __ATOMIC_ACQUIRE, __HIP_MEMORY_SCOPE_AGENT) < ep){
      __builtin_amdgcn_s_sleep(2);
      if (++spins > (1 << 26)) break;   // safety escape -> visible wrong result, not a hang
    }
    __threadfence();
  }
  __syncthreads();
}

// ---------- weight convert/transpose: dst[c][h][k] bf16, swizzled, scaled ----------
__global__ __launch_bounds__(256) void pose_convT(const float* __restrict__ src,
    uint16_t* __restrict__ dst, int N, int MOD, int CB, float scale)
{
  __shared__ float tile[32][256];
  int bk = blockIdx.x & 3, bn = blockIdx.x >> 2;
  int k0 = bk * 32, n0 = bn * 256;
  int t = threadIdx.x;
  for (int r = 0; r < 32; r++){
    int n = n0 + t;
    tile[r][t] = (n < N) ? src[(size_t)(k0 + r) * N + n] : 0.f;
  }
  __syncthreads();
  int n = n0 + t;
  if (n < N){
    int c = n % MOD, h = n / MOD;
    #pragma unroll
    for (int o = 0; o < 4; o++){
      uint32_t w0 = (uint32_t)f2bf(tile[o*8+0][t]*scale) | ((uint32_t)f2bf(tile[o*8+1][t]*scale) << 16);
      uint32_t w1 = (uint32_t)f2bf(tile[o*8+2][t]*scale) | ((uint32_t)f2bf(tile[o*8+3][t]*scale) << 16);
      uint32_t w2 = (uint32_t)f2bf(tile[o*8+4][t]*scale) | ((uint32_t)f2bf(tile[o*8+5][t]*scale) << 16);
      uint32_t w3 = (uint32_t)f2bf(tile[o*8+6][t]*scale) | ((uint32_t)f2bf(tile[o*8+7][t]*scale) << 16);
      i32x4 val = { (int)w0, (int)w1, (int)w2, (int)w3 };
      uint32_t byte = (uint32_t)c * (uint32_t)CB + aoff((uint32_t)h, (uint32_t)(k0 + o*8) * 2);
      *(i32x4*)((char*)dst + byte) = val;
    }
  }
}

// ---------- bo_c[c][h] = b_out[h*129+c]*SCALE ; d0g[0][b] = ts[b,2]-ts[b,1] ----------
__global__ __launch_bounds__(256) void pose_misc(const float* __restrict__ b_out,
    const float* __restrict__ ts, float* __restrict__ bo_c, float* __restrict__ d0g)
{
  int i = blockIdx.x * 256 + threadIdx.x;
  if (i < 16512){
    int c = i % 129, h = i / 129;
    bo_c[c*128 + h] = b_out[i] * 2.8853900817779268f;
  }
  if (i < 1024) d0g[i] = ts[i*12 + 2] - ts[i*12 + 1];
}

// ---------- fused rows l=0,1 (f32 exact): F0, d0g[1+h][b] ----------
__global__ __launch_bounds__(256) void pose_fused(
    const float* __restrict__ fv, const float* __restrict__ fi,
    const float* __restrict__ w_red, const float* __restrict__ b_red,
    float* __restrict__ F0, float* __restrict__ d0g)
{
  __shared__ float pk[128][16];
  __shared__ float res[16][128];
  const int b0 = blockIdx.x * 8;
  const int t = threadIdx.x;
  const int h = t & 127, sg = t >> 7;
  float acc[8] = {0.f,0.f,0.f,0.f,0.f,0.f,0.f,0.f};
  for (int p = 0; p < 6; p++){
    __syncthreads();
    { const int s  = t >> 4;
      const int ch = (t & 15) * 8;
      const int b  = b0 + (s & 7);
      const int ll = s >> 3;
      const int kb = p*128 + ch;
      const float* src = (kb < 512) ? (fv + ((size_t)b*11 + ll)*512 + kb)
                                    : (fi + ((size_t)b*11 + ll)*256 + (kb - 512));
      float v[8];
      #pragma unroll
      for (int j = 0; j < 8; j++) v[j] = src[j];
      #pragma unroll
      for (int j = 0; j < 8; j++) pk[ch + j][s] = v[j];
    }
    __syncthreads();
    #pragma unroll 4
    for (int kk = 0; kk < 128; kk++){
      const float wv = w_red[(size_t)(p*128 + kk)*128 + h];
      f32x4 v0 = *(const f32x4*)&pk[kk][sg*8];
      f32x4 v1 = *(const f32x4*)&pk[kk][sg*8 + 4];
      acc[0] += v0.x*wv; acc[1] += v0.y*wv; acc[2] += v0.z*wv; acc[3] += v0.w*wv;
      acc[4] += v1.x*wv; acc[5] += v1.y*wv; acc[6] += v1.z*wv; acc[7] += v1.w*wv;
    }
  }
  __syncthreads();
  const float br = b_red[h];
  #pragma unroll
  for (int si = 0; si < 8; si++) res[sg*8 + si][h] = acc[si] + br;
  __syncthreads();
  if (sg == 0){
    #pragma unroll
    for (int si = 0; si < 8; si++){
      const int b = b0 + si;
      const float f0 = res[si][h];
      const float f1 = res[8 + si][h];
      F0[(size_t)b*128 + h] = f0;
      d0g[(size_t)(1 + h)*1024 + b] = f1 - f0;
    }
  }
}

// ---------- z0 = x0 @ w_init + b_init (f32); also S[b] = sum_c d0 ----------
__global__ __launch_bounds__(512) void pose_init(
    const float* __restrict__ F0, const float* __restrict__ ts,
    const float* __restrict__ w_init, const float* __restrict__ b_init,
    const float* __restrict__ d0g,
    float* __restrict__ z_base, uint16_t* __restrict__ zbuf,
    float* __restrict__ hT, float* __restrict__ S)
{
  __shared__ float Ft[128][64];
  const int b0 = blockIdx.x * 64;
  const int t = threadIdx.x;
  { const int b = t >> 3, ch = (t & 7)*16;
    #pragma unroll
    for (int j = 0; j < 16; j++) Ft[ch + j][b] = F0[(size_t)(b0 + b)*128 + ch + j];
  }
  __syncthreads();
  const int h = t & 127, rg = t >> 7;
  float acc[16];
  const float w0 = w_init[h], bi = b_init[h];
  #pragma unroll
  for (int r = 0; r < 16; r++){
    const int b = b0 + rg*16 + r;
    acc[r] = (ts[b*12 + 1] - ts[b*12 + 0]) * w0 + bi;
  }
  #pragma unroll 2
  for (int j = 0; j < 128; j++){
    const float wv = w_init[(j + 1)*128 + h];
    const float* pr = &Ft[j][rg*16];
    #pragma unroll
    for (int q = 0; q < 4; q++){
      f32x4 v = *(const f32x4*)(pr + q*4);
      acc[q*4+0] += v.x*wv; acc[q*4+1] += v.y*wv; acc[q*4+2] += v.z*wv; acc[q*4+3] += v.w*wv;
    }
  }
  #pragma unroll
  for (int r = 0; r < 16; r++){
    const int b = b0 + rg*16 + r;
    const float z = acc[r];
    z_base[(size_t)b*128 + h] = z;
    hT[(size_t)b*1280 + h] = z;
    const int bl = b & 127;
    uint32_t byte = (uint32_t)(b >> 7) * 32768u + aoff((uint32_t)bl, (uint32_t)h*2);
    *(uint16_t*)((char*)zbuf + byte) = f2bf(z);
  }
  if (t < 64){
    const int b = b0 + t;
    float s = 0.f;
    for (int c = 0; c < 129; c++) s += d0g[(size_t)c*1024 + b];
    S[b] = s;
  }
}

// ---------- persistent: 144 evals, 2 grid barriers each ----------
__global__ __launch_bounds__(512) void pose_persist(
    const uint16_t* __restrict__ Wt, const uint16_t* __restrict__ w1t,
    const uint16_t* __restrict__ w2t,
    const float* __restrict__ b1, const float* __restrict__ b2,
    const float* __restrict__ bo_c, const float* __restrict__ d0g,
    const float* __restrict__ Sv,
    uint16_t* __restrict__ zbuf, float* __restrict__ partials,
    const float* __restrict__ z_base,
    float* __restrict__ hT, uint32_t* __restrict__ bar)
{
  __shared__ uint16_t A0[16384], A1[16384], W0[16384], W1b[16384]; // 4 x 32 KiB
  const int t   = threadIdx.x;
  const int blk = blockIdx.x;
  const int grp = blk & 7;                                 // barrier group / XCD
  const int mi  = blk >> 5;                                // team (128 batch rows)
  const int ci  = (blk & 7)*4 + ((blk >> 3) & 3);          // chunk, XCD-localized
  const int nc  = (ci == 31) ? 5 : 4;
  const int cbase = ci * 4;
  const int l  = t & 63, w = t >> 6;
  const int hh = w >> 2, bq = w & 3;                       // wave tile [64 h][32 b]
  const int l15 = l & 15, l4 = l >> 4;

  // phase-B ownership: thread <-> (bB, hBv), state lives in registers forever
  const int idxB = blk*512 + t;
  const int bB = idxB >> 7, hBv = idxB & 127;
  const float HS = 0x1.999996p-6f;                         // jax f32 hstep
  const float C2 = HS * 0.5f, C6 = HS / 6.f;
  float zb = z_base[(size_t)bB*128 + hBv];                 // RK4 base state (reg)
  float av = 0.f;                                          // k-accumulator (reg)
  const float Sb = Sv[bB];
  const uint32_t zbyte = (uint32_t)(bB >> 7)*32768u + aoff((uint32_t)(bB & 127), (uint32_t)hBv*2);

  i32x4 Ra[4], Rb[4], Rc[4];
  auto ldst = [&](const void* g, i32x4* r){
    const i32x4* s = (const i32x4*)g;
    #pragma unroll
    for (int i = 0; i < 4; i++) r[i] = s[t + 512*i];
  };
  auto wrst = [&](uint16_t* lds, const i32x4* r){
    i32x4* d = (i32x4*)lds;
    #pragma unroll
    for (int i = 0; i < 4; i++) d[t + 512*i] = r[i];
  };
  auto chain = [&](const uint16_t* Wl, const uint16_t* Bl, const float* bias, uint16_t* Dl){
    bf16x8 bfr[2][4];
    #pragma unroll
    for (int ct = 0; ct < 2; ct++){
      const int col = bq*32 + ct*16 + l15;
      #pragma unroll
      for (int kb = 0; kb < 4; kb++)
        bfr[ct][kb] = *(const bf16x8*)((const char*)Bl + aoff((uint32_t)col, kb*64 + l4*16));
    }
    #pragma unroll
    for (int rt = 0; rt < 4; rt++){
      const int row = hh*64 + rt*16 + l15;
      bf16x8 afr[4];
      #pragma unroll
      for (int kb = 0; kb < 4; kb++)
        afr[kb] = *(const bf16x8*)((const char*)Wl + aoff((uint32_t)row, kb*64 + l4*16));
      const int h0 = hh*64 + rt*16 + l4*4;
      const f32x4 bias4 = *(const f32x4*)(bias + h0);
      #pragma unroll
      for (int ct = 0; ct < 2; ct++){
        f32x4 acc = {0.f,0.f,0.f,0.f};
        #pragma unroll
        for (int kb = 0; kb < 4; kb++) acc = MFMA(afr[kb], bfr[ct][kb], acc);
        const int col = bq*32 + ct*16 + l15;
        const float r0 = fmaxf(acc.x + bias4.x, 0.f);
        const float r1 = fmaxf(acc.y + bias4.y, 0.f);
        const float r2 = fmaxf(acc.z + bias4.z, 0.f);
        const float r3 = fmaxf(acc.w + bias4.w, 0.f);
        i32x2 pv = { (int)pkbf(r0, r1), (int)pkbf(r2, r3) };
        *(i32x2*)((char*)Dl + aoff((uint32_t)col, (uint32_t)h0*2)) = pv;
      }
    }
  };

  #pragma unroll 1
  for (int e = 0; e < 144; e++){
    // ================= phase A: field eval =================
    f32x4 out[4][2];
    const f32x4 Z4 = {0.f,0.f,0.f,0.f};
    #pragma unroll
    for (int rt = 0; rt < 4; rt++){ out[rt][0] = Z4; out[rt][1] = Z4; }

    ldst((const char*)zbuf + (size_t)mi*32768, Ra);
    ldst(w1t, Rb);
    ldst(w2t, Rc);
    wrst(A0, Ra); wrst(W0, Rb); wrst(W1b, Rc);
    __syncthreads();

    ldst((const char*)Wt + (size_t)cbase*32768, Ra);       // c0 in flight
    chain(W0, A0, b1, A1);                                  // h1
    __syncthreads();

    wrst(W0, Ra);                                           // c0 -> W0
    ldst((const char*)Wt + (size_t)(cbase+1)*32768, Rb);    // c1 in flight
    chain(W1b, A1, b2, A0);                                 // h2
    __syncthreads();

    bf16x8 bfr[2][4];                                       // h2 B-frags, constant over c
    #pragma unroll
    for (int ct = 0; ct < 2; ct++){
      const int col = bq*32 + ct*16 + l15;
      #pragma unroll
      for (int kb = 0; kb < 4; kb++)
        bfr[ct][kb] = *(const bf16x8*)((const char*)A0 + aoff((uint32_t)col, kb*64 + l4*16));
    }

    for (int k = 0; k < nc; k++){
      const int c = cbase + k;
      const uint16_t* Wl = (k & 1) ? W1b : W0;
      float d0v[2];
      d0v[0] = d0g[(size_t)c*1024 + mi*128 + bq*32 + l15];
      d0v[1] = d0g[(size_t)c*1024 + mi*128 + bq*32 + 16 + l15];
      #pragma unroll
      for (int rt = 0; rt < 4; rt++){
        const int row = hh*64 + rt*16 + l15;
        bf16x8 afr[4];
        #pragma unroll
        for (int kb = 0; kb < 4; kb++)
          afr[kb] = *(const bf16x8*)((const char*)Wl + aoff((uint32_t)row, kb*64 + l4*16));
        const int h0 = hh*64 + rt*16 + l4*4;
        const f32x4 bo4 = *(const f32x4*)(bo_c + c*128 + h0);
        #pragma unroll
        for (int ct = 0; ct < 2; ct++){
          f32x4 acc = {0.f,0.f,0.f,0.f};
          #pragma unroll
          for (int kb = 0; kb < 4; kb++) acc = MFMA(afr[kb], bfr[ct][kb], acc);
          f32x4 rr;
          rr.x = __builtin_amdgcn_rcpf(__builtin_amdgcn_exp2f(acc.x + bo4.x) + 1.f);
          rr.y = __builtin_amdgcn_rcpf(__builtin_amdgcn_exp2f(acc.y + bo4.y) + 1.f);
          rr.z = __builtin_amdgcn_rcpf(__builtin_amdgcn_exp2f(acc.z + bo4.z) + 1.f);
          rr.w = __builtin_amdgcn_rcpf(__builtin_amdgcn_exp2f(acc.w + bo4.w) + 1.f);
          out[rt][ct] += rr * d0v[ct];
        }
      }
      if (k + 1 < nc) wrst((k & 1) ? W0 : W1b, (k & 1) ? Ra : Rb);
      if (k + 2 < nc) ldst((const char*)Wt + (size_t)(cbase+k+2)*32768, (k & 1) ? Rb : Ra);
      __syncthreads();
    }

    #pragma unroll
    for (int rt = 0; rt < 4; rt++){
      const int h0 = hh*64 + rt*16 + l4*4;
      #pragma unroll
      for (int ct = 0; ct < 2; ct++){
        const int b = mi*128 + bq*32 + ct*16 + l15;
        *(f32x4*)(partials + ((size_t)ci*1024 + b)*128 + h0) = out[rt][ct];
      }
    }

    gridbar(bar, (uint32_t)(2*e + 1), grp);

    // ================= phase B: reduce + RK4 update =================
    {
      float s = 0.f;
      #pragma unroll 8
      for (int sl = 0; sl < 32; sl++)
        s += partials[((size_t)sl*1024 + bB)*128 + hBv];
      const float kk = Sb - 2.f*s;
      const int st = e & 3;
      float ze;
      if (st == 0){      av = kk;        ze = zb + C2*kk; }
      else if (st == 1){ av += 2.f*kk;   ze = zb + C2*kk; }
      else if (st == 2){ av += 2.f*kk;   ze = zb + HS*kk; }
      else {
        zb += C6*(av + kk);
        ze = zb;
        if ((e & 15) == 15)
          hT[(size_t)bB*1280 + (size_t)((e >> 4) + 1)*128 + hBv] = zb;
      }
      *(uint16_t*)((char*)zbuf + zbyte) = f2bf(ze);
    }

    gridbar(bar, (uint32_t)(2*e + 2), grp);
  }
}

// ---------- readout: poses = leaky(hT @ w_r1 + b_r1) @ w_r2 + b_r2 ; z_final copy ----------
__global__ __launch_bounds__(256) void pose_readout(
    const float* __restrict__ hT, const float* __restrict__ w_r1, const float* __restrict__ b_r1,
    const float* __restrict__ w_r2, const float* __restrict__ b_r2,
    float* __restrict__ out_poses, float* __restrict__ out_z)
{
  if (blockIdx.x >= 320){
    const int cb = blockIdx.x - 320;
    const int base = cb*2048 + threadIdx.x*4;
    #pragma unroll
    for (int p = 0; p < 2; p++){
      const int i = base + p*1024;
      const int b = i >> 7, h = i & 127;
      *(f32x4*)(out_z + i) = *(const f32x4*)(hT + (size_t)b*1280 + 1152 + h);
    }
    return;
  }
  __shared__ float htl[128][32];
  __shared__ float al[32][128];
  const int r0 = blockIdx.x * 32;
  const int t = threadIdx.x;
  { const int row = t >> 3, ch = (t & 7)*16;
    #pragma unroll
    for (int j = 0; j < 16; j++)
      htl[ch + j][row] = hT[(size_t)(r0 + row)*128 + ch + j];
  }
  __syncthreads();
  const int j = t & 127, rg = t >> 7;
  float a[16];
  const float bj = b_r1[j];
  #pragma unroll
  for (int r = 0; r < 16; r++) a[r] = bj;
  #pragma unroll 2
  for (int kk = 0; kk < 128; kk++){
    const float wv = w_r1[(size_t)kk*128 + j];
    const float* pr = &htl[kk][rg*16];
    #pragma unroll
    for (int q = 0; q < 4; q++){
      f32x4 v = *(const f32x4*)(pr + q*4);
      a[q*4+0] += v.x*wv; a[q*4+1] += v.y*wv; a[q*4+2] += v.z*wv; a[q*4+3] += v.w*wv;
    }
  }
  #pragma unroll
  for (int r = 0; r < 16; r++){
    float v = a[r];
    al[rg*16 + r][j] = (v > 0.f) ? v : 0.1f*v;
  }
  __syncthreads();
  if (t < 192){
    const int row = t / 6, p = t % 6;
    float s = b_r2[p];
    const float* ar = al[row];
    #pragma unroll 4
    for (int jj = 0; jj < 128; jj++) s += ar[jj] * w_r2[jj*6 + p];
    out_poses[(size_t)(r0 + row)*6 + p] = s;
  }
}

// ---------- host ----------
extern "C" void kernel_launch(void* const* d_in, const int* in_sizes, int n_in,
                              void* d_out, int out_size, void* d_ws, size_t ws_size,
                              hipStream_t stream)
{
  (void)in_sizes; (void)n_in; (void)out_size; (void)ws_size;
  const float* fv    = (const float*)d_in[0];
  const float* fi    = (const float*)d_in[1];
  const float* ts    = (const float*)d_in[2];
  const float* w_red = (const float*)d_in[3];
  const float* b_red = (const float*)d_in[4];
  const float* w_init= (const float*)d_in[5];
  const float* b_init= (const float*)d_in[6];
  const float* w_h1  = (const float*)d_in[7];
  const float* b_h1  = (const float*)d_in[8];
  const float* w_h2  = (const float*)d_in[9];
  const float* b_h2  = (const float*)d_in[10];
  const float* w_out = (const float*)d_in[11];
  const float* b_out = (const float*)d_in[12];
  const float* w_r1  = (const float*)d_in[13];
  const float* b_r1  = (const float*)d_in[14];
  const float* w_r2  = (const float*)d_in[15];
  const float* b_r2  = (const float*)d_in[16];

  char* p = (char*)d_ws;
  auto take = [&](size_t n){ char* r = p; p += (n + 255) & ~(size_t)255; return r; };
  uint32_t* bar   = (uint32_t*)take(4096);                // barrier state (zeroed per call)
  uint16_t* Wt    = (uint16_t*)take((size_t)129*32768);   // [c][h][k] bf16 swz, x 2log2e
  uint16_t* w1t   = (uint16_t*)take(32768);
  uint16_t* w2t   = (uint16_t*)take(32768);
  float* bo_c     = (float*)take((size_t)129*128*4);
  float* d0g      = (float*)take((size_t)129*1024*4);
  float* Sv       = (float*)take(1024*4);
  float* F0       = (float*)take((size_t)1024*128*4);
  float* z_base   = (float*)take((size_t)1024*128*4);
  uint16_t* zbuf  = (uint16_t*)take((size_t)8*32768);
  float* hT       = (float*)take((size_t)1024*10*128*4);
  float* partials = (float*)take((size_t)32*1024*128*4);

  float* out_poses = (float*)d_out;
  float* out_z     = (float*)d_out + 61440;

  const float SC = 2.8853900817779268f;  // 2*log2(e)

  hipMemsetAsync(bar, 0, 4096, stream);
  pose_convT<<<4,   256, 0, stream>>>(w_h1,  w1t, 128,   1,   0,     1.0f);
  pose_convT<<<4,   256, 0, stream>>>(w_h2,  w2t, 128,   1,   0,     1.0f);
  pose_convT<<<260, 256, 0, stream>>>(w_out, Wt,  16512, 129, 32768, SC);
  pose_misc <<<65,  256, 0, stream>>>(b_out, ts, bo_c, d0g);
  pose_fused<<<128, 256, 0, stream>>>(fv, fi, w_red, b_red, F0, d0g);
  pose_init <<<16,  512, 0, stream>>>(F0, ts, w_init, b_init, d0g, z_base, zbuf, hT, Sv);

  pose_persist<<<256, 512, 0, stream>>>(Wt, w1t, w2t, b_h1, b_h2, bo_c, d0g, Sv,
                                        zbuf, partials, z_base, hT, bar);

  pose_readout<<<384, 256, 0, stream>>>(hT, w_r1, b_r1, w_r2, b_r2, out_poses, out_z);
}

// Round 3
// 5275.651 us; speedup vs baseline: 2.6814x; 2.6814x over previous
//
#include <hip/hip_runtime.h>
#include <stdint.h>

typedef float   f32x4 __attribute__((ext_vector_type(4)));
typedef float   f32x2 __attribute__((ext_vector_type(2)));
typedef int     i32x4 __attribute__((ext_vector_type(4)));
typedef int     i32x2 __attribute__((ext_vector_type(2)));
typedef __bf16  bf16x8 __attribute__((ext_vector_type(8)));

#define DEV __device__ __forceinline__

// ---------- helpers ----------
DEV uint16_t f2bf(float f){                       // RNE f32->bf16
  uint32_t u = __float_as_uint(f);
  u += 0x7fffu + ((u >> 16) & 1u);
  return (uint16_t)(u >> 16);
}
DEV uint32_t pkbf(float lo, float hi){            // pack 2 bf16 into u32
  uint32_t r;
  asm("v_cvt_pk_bf16_f32 %0, %1, %2" : "=v"(r) : "v"(lo), "v"(hi));
  return r;
}
// byte offset inside a [row][128 bf16] tile with XOR-16B bank swizzle
DEV uint32_t aoff(uint32_t row, uint32_t q){ return (row << 8) + (q ^ ((row & 7u) << 4)); }

DEV f32x4 MFMA(bf16x8 a, bf16x8 b, f32x4 c){
  return __builtin_amdgcn_mfma_f32_16x16x32_bf16(a, b, c, 0, 0, 0);
}

// ---------- fence-free grid barrier (relaxed atomics only; bar zeroed per call) ----------
// layout (u32 idx): group counters at g*32 (8 groups, 128B apart), root at 256, go-word at 288
DEV void bar_arrive(uint32_t* bar, uint32_t ep, int grp){
  // caller guarantees: __syncthreads() already drained this block's vmem
  uint32_t a = __hip_atomic_fetch_add(bar + grp*32, 1u, __ATOMIC_RELAXED, __HIP_MEMORY_SCOPE_AGENT);
  if (a == 32u*ep - 1u){
    uint32_t r = __hip_atomic_fetch_add(bar + 256, 1u, __ATOMIC_RELAXED, __HIP_MEMORY_SCOPE_AGENT);
    if (r == 8u*ep - 1u)
      __hip_atomic_store(bar + 288, ep, __ATOMIC_RELAXED, __HIP_MEMORY_SCOPE_AGENT);
  }
}
DEV void bar_wait(uint32_t* bar, uint32_t ep){
  int spins = 0;
  while (__hip_atomic_load(bar + 288, __ATOMIC_RELAXED, __HIP_MEMORY_SCOPE_AGENT) < ep){
    __builtin_amdgcn_s_sleep(1);
    if (++spins > (1 << 17)) break;   // safety escape -> visible wrong result, not a hang
  }
  asm volatile("" ::: "memory");
}

// ---------- weight convert/transpose: dst[c][h][k] bf16, swizzled, scaled ----------
__global__ __launch_bounds__(256) void pose_convT(const float* __restrict__ src,
    uint16_t* __restrict__ dst, int N, int MOD, int CB, float scale)
{
  __shared__ float tile[32][256];
  int bk = blockIdx.x & 3, bn = blockIdx.x >> 2;
  int k0 = bk * 32, n0 = bn * 256;
  int t = threadIdx.x;
  for (int r = 0; r < 32; r++){
    int n = n0 + t;
    tile[r][t] = (n < N) ? src[(size_t)(k0 + r) * N + n] : 0.f;
  }
  __syncthreads();
  int n = n0 + t;
  if (n < N){
    int c = n % MOD, h = n / MOD;
    #pragma unroll
    for (int o = 0; o < 4; o++){
      uint32_t w0 = (uint32_t)f2bf(tile[o*8+0][t]*scale) | ((uint32_t)f2bf(tile[o*8+1][t]*scale) << 16);
      uint32_t w1 = (uint32_t)f2bf(tile[o*8+2][t]*scale) | ((uint32_t)f2bf(tile[o*8+3][t]*scale) << 16);
      uint32_t w2 = (uint32_t)f2bf(tile[o*8+4][t]*scale) | ((uint32_t)f2bf(tile[o*8+5][t]*scale) << 16);
      uint32_t w3 = (uint32_t)f2bf(tile[o*8+6][t]*scale) | ((uint32_t)f2bf(tile[o*8+7][t]*scale) << 16);
      i32x4 val = { (int)w0, (int)w1, (int)w2, (int)w3 };
      uint32_t byte = (uint32_t)c * (uint32_t)CB + aoff((uint32_t)h, (uint32_t)(k0 + o*8) * 2);
      *(i32x4*)((char*)dst + byte) = val;
    }
  }
}

// ---------- bo_c[c][h] = b_out[h*129+c]*SCALE ; d0g[0][b] = ts[b,2]-ts[b,1] ----------
__global__ __launch_bounds__(256) void pose_misc(const float* __restrict__ b_out,
    const float* __restrict__ ts, float* __restrict__ bo_c, float* __restrict__ d0g)
{
  int i = blockIdx.x * 256 + threadIdx.x;
  if (i < 16512){
    int c = i % 129, h = i / 129;
    bo_c[c*128 + h] = b_out[i] * 2.8853900817779268f;
  }
  if (i < 1024) d0g[i] = ts[i*12 + 2] - ts[i*12 + 1];
}

// ---------- fused rows l=0,1 (f32 exact): F0, d0g[1+h][b] ----------
__global__ __launch_bounds__(256) void pose_fused(
    const float* __restrict__ fv, const float* __restrict__ fi,
    const float* __restrict__ w_red, const float* __restrict__ b_red,
    float* __restrict__ F0, float* __restrict__ d0g)
{
  __shared__ float pk[128][16];
  __shared__ float res[16][128];
  const int b0 = blockIdx.x * 8;
  const int t = threadIdx.x;
  const int h = t & 127, sg = t >> 7;
  float acc[8] = {0.f,0.f,0.f,0.f,0.f,0.f,0.f,0.f};
  for (int p = 0; p < 6; p++){
    __syncthreads();
    { const int s  = t >> 4;
      const int ch = (t & 15) * 8;
      const int b  = b0 + (s & 7);
      const int ll = s >> 3;
      const int kb = p*128 + ch;
      const float* src = (kb < 512) ? (fv + ((size_t)b*11 + ll)*512 + kb)
                                    : (fi + ((size_t)b*11 + ll)*256 + (kb - 512));
      float v[8];
      #pragma unroll
      for (int j = 0; j < 8; j++) v[j] = src[j];
      #pragma unroll
      for (int j = 0; j < 8; j++) pk[ch + j][s] = v[j];
    }
    __syncthreads();
    #pragma unroll 4
    for (int kk = 0; kk < 128; kk++){
      const float wv = w_red[(size_t)(p*128 + kk)*128 + h];
      f32x4 v0 = *(const f32x4*)&pk[kk][sg*8];
      f32x4 v1 = *(const f32x4*)&pk[kk][sg*8 + 4];
      acc[0] += v0.x*wv; acc[1] += v0.y*wv; acc[2] += v0.z*wv; acc[3] += v0.w*wv;
      acc[4] += v1.x*wv; acc[5] += v1.y*wv; acc[6] += v1.z*wv; acc[7] += v1.w*wv;
    }
  }
  __syncthreads();
  const float br = b_red[h];
  #pragma unroll
  for (int si = 0; si < 8; si++) res[sg*8 + si][h] = acc[si] + br;
  __syncthreads();
  if (sg == 0){
    #pragma unroll
    for (int si = 0; si < 8; si++){
      const int b = b0 + si;
      const float f0 = res[si][h];
      const float f1 = res[8 + si][h];
      F0[(size_t)b*128 + h] = f0;
      d0g[(size_t)(1 + h)*1024 + b] = f1 - f0;
    }
  }
}

// ---------- z0 = x0 @ w_init + b_init (f32); also S[b] = sum_c d0 ----------
__global__ __launch_bounds__(512) void pose_init(
    const float* __restrict__ F0, const float* __restrict__ ts,
    const float* __restrict__ w_init, const float* __restrict__ b_init,
    const float* __restrict__ d0g,
    float* __restrict__ z_base, uint16_t* __restrict__ zbuf,
    float* __restrict__ hT, float* __restrict__ S)
{
  __shared__ float Ft[128][64];
  const int b0 = blockIdx.x * 64;
  const int t = threadIdx.x;
  { const int b = t >> 3, ch = (t & 7)*16;
    #pragma unroll
    for (int j = 0; j < 16; j++) Ft[ch + j][b] = F0[(size_t)(b0 + b)*128 + ch + j];
  }
  __syncthreads();
  const int h = t & 127, rg = t >> 7;
  float acc[16];
  const float w0 = w_init[h], bi = b_init[h];
  #pragma unroll
  for (int r = 0; r < 16; r++){
    const int b = b0 + rg*16 + r;
    acc[r] = (ts[b*12 + 1] - ts[b*12 + 0]) * w0 + bi;
  }
  #pragma unroll 2
  for (int j = 0; j < 128; j++){
    const float wv = w_init[(j + 1)*128 + h];
    const float* pr = &Ft[j][rg*16];
    #pragma unroll
    for (int q = 0; q < 4; q++){
      f32x4 v = *(const f32x4*)(pr + q*4);
      acc[q*4+0] += v.x*wv; acc[q*4+1] += v.y*wv; acc[q*4+2] += v.z*wv; acc[q*4+3] += v.w*wv;
    }
  }
  #pragma unroll
  for (int r = 0; r < 16; r++){
    const int b = b0 + rg*16 + r;
    const float z = acc[r];
    z_base[(size_t)b*128 + h] = z;
    hT[(size_t)b*1280 + h] = z;
    const int bl = b & 127;
    uint32_t byte = (uint32_t)(b >> 7) * 32768u + aoff((uint32_t)bl, (uint32_t)h*2);
    *(uint16_t*)((char*)zbuf + byte) = f2bf(z);
  }
  if (t < 64){
    const int b = b0 + t;
    float s = 0.f;
    for (int c = 0; c < 129; c++) s += d0g[(size_t)c*1024 + b];
    S[b] = s;
  }
}

// ---------- persistent: 144 evals; fence-free barriers; sc1 data plane ----------
__global__ __launch_bounds__(512) void pose_persist(
    const uint16_t* __restrict__ Wt, const uint16_t* __restrict__ w1t,
    const uint16_t* __restrict__ w2t,
    const float* __restrict__ b1, const float* __restrict__ b2,
    const float* __restrict__ bo_c, const float* __restrict__ d0g,
    const float* __restrict__ Sv,
    uint16_t* __restrict__ zbuf, float* __restrict__ partials,
    const float* __restrict__ z_base,
    float* __restrict__ hT, uint32_t* __restrict__ bar)
{
  __shared__ uint16_t Xb[16384], Yb[16384], Pb[16384], Qb[16384]; // 4 x 32 KiB
  const int t   = threadIdx.x;
  const int blk = blockIdx.x;
  const int grp = blk & 7;
  const int mi  = blk >> 5;                                // team (XCD-spread, L2-local Wt chunks)
  const int ci  = (blk & 7)*4 + ((blk >> 3) & 3);          // chunk, XCD-localized
  const int nc  = (ci == 31) ? 5 : 4;
  const int cbase = ci * 4;
  const int l  = t & 63, w = t >> 6;
  const int hh = w >> 2, bq = w & 3;                       // wave tile [64 h][32 b]
  const int l15 = l & 15, l4 = l >> 4;

  // phase-B ownership: pair (bB, hp2/hp2+1) lives in registers forever
  const int pg = blk*256 + (t & 255);
  const int bB = pg >> 6, hp2 = (pg & 63)*2;
  const float HS = 0x1.999996p-6f;                         // jax f32 hstep
  const float C2 = HS * 0.5f, C6 = HS / 6.f;
  float zb0 = z_base[(size_t)bB*128 + hp2];
  float zb1 = z_base[(size_t)bB*128 + hp2 + 1];
  float av0 = 0.f, av1 = 0.f;
  const float Sb = Sv[bB];
  const uint32_t zbyte = (uint32_t)(bB >> 7)*32768u + aoff((uint32_t)(bB & 127), (uint32_t)hp2*2);
  const char* zsl = (const char*)zbuf + (size_t)mi*32768;

  i32x4 Ra[4];
  auto ldst = [&](const void* g, i32x4* r){
    const i32x4* s = (const i32x4*)g;
    #pragma unroll
    for (int i = 0; i < 4; i++) r[i] = s[t + 512*i];
  };
  auto wrst = [&](uint16_t* lds, const i32x4* r){
    i32x4* d = (i32x4*)lds;
    #pragma unroll
    for (int i = 0; i < 4; i++) d[t + 512*i] = r[i];
  };
  // generic chain GEMM with B-operand fragments given in regs
  auto chain_core = [&](const uint16_t* Wl, const bf16x8 (&bfr)[2][4], const float* bias, uint16_t* Dl){
    #pragma unroll
    for (int rt = 0; rt < 4; rt++){
      const int row = hh*64 + rt*16 + l15;
      bf16x8 afr[4];
      #pragma unroll
      for (int kb = 0; kb < 4; kb++)
        afr[kb] = *(const bf16x8*)((const char*)Wl + aoff((uint32_t)row, kb*64 + l4*16));
      const int h0 = hh*64 + rt*16 + l4*4;
      const f32x4 bias4 = *(const f32x4*)(bias + h0);
      #pragma unroll
      for (int ct = 0; ct < 2; ct++){
        f32x4 acc = {0.f,0.f,0.f,0.f};
        #pragma unroll
        for (int kb = 0; kb < 4; kb++) acc = MFMA(afr[kb], bfr[ct][kb], acc);
        const int col = bq*32 + ct*16 + l15;
        const float r0 = fmaxf(acc.x + bias4.x, 0.f);
        const float r1 = fmaxf(acc.y + bias4.y, 0.f);
        const float r2 = fmaxf(acc.z + bias4.z, 0.f);
        const float r3 = fmaxf(acc.w + bias4.w, 0.f);
        i32x2 pv = { (int)pkbf(r0, r1), (int)pkbf(r2, r3) };
        *(i32x2*)((char*)Dl + aoff((uint32_t)col, (uint32_t)h0*2)) = pv;
      }
    }
  };
  auto ld_bfr_lds = [&](const uint16_t* Bl, bf16x8 (&bfr)[2][4]){
    #pragma unroll
    for (int ct = 0; ct < 2; ct++){
      const int col = bq*32 + ct*16 + l15;
      #pragma unroll
      for (int kb = 0; kb < 4; kb++)
        bfr[ct][kb] = *(const bf16x8*)((const char*)Bl + aoff((uint32_t)col, kb*64 + l4*16));
    }
  };

  // ---- prologue staging: w1->Xb, w2->Yb (resident), c0->Pb, c1->Ra
  { i32x4 R0[4], R1[4], R2[4];
    ldst(w1t, R1); ldst(w2t, R2);
    ldst((const char*)Wt + (size_t)cbase*32768, R0);
    ldst((const char*)Wt + (size_t)(cbase + 1)*32768, Ra);
    wrst(Xb, R1); wrst(Yb, R2); wrst(Pb, R0);
  }
  __syncthreads();

  #pragma unroll 1
  for (int e = 0; e < 144; e++){
    // ========== phase A ==========
    // z B-fragments straight from global (sc1, bypass L2)
    bf16x8 bz[2][4];
    #pragma unroll
    for (int ct = 0; ct < 2; ct++){
      const int col = bq*32 + ct*16 + l15;
      #pragma unroll
      for (int kb = 0; kb < 4; kb++){
        const char* a = zsl + aoff((uint32_t)col, kb*64 + l4*16);
        union { uint64_t q[2]; bf16x8 v; } u;
        u.q[0] = __hip_atomic_load((const uint64_t*)a,     __ATOMIC_RELAXED, __HIP_MEMORY_SCOPE_AGENT);
        u.q[1] = __hip_atomic_load((const uint64_t*)(a+8), __ATOMIC_RELAXED, __HIP_MEMORY_SCOPE_AGENT);
        bz[ct][kb] = u.v;
      }
    }
    chain_core(Xb, bz, b1, Qb);            // h1 = relu(w1 . z) -> Qb
    __syncthreads();
    { bf16x8 bh1[2][4];
      ld_bfr_lds(Qb, bh1);
      chain_core(Yb, bh1, b2, Xb);         // h2 = relu(w2 . h1) -> Xb
    }
    __syncthreads();

    bf16x8 bfr[2][4];                      // h2 B-frags, constant over chunks
    ld_bfr_lds(Xb, bfr);

    f32x4 out[4][2];
    const f32x4 Z4 = {0.f,0.f,0.f,0.f};
    #pragma unroll
    for (int rt = 0; rt < 4; rt++){ out[rt][0] = Z4; out[rt][1] = Z4; }

    for (int k = 0; k < nc; k++){
      const int c = cbase + k;
      const uint16_t* Wl = (k & 1) ? Qb : Pb;
      float d0v[2];
      d0v[0] = d0g[(size_t)c*1024 + mi*128 + bq*32 + l15];
      d0v[1] = d0g[(size_t)c*1024 + mi*128 + bq*32 + 16 + l15];
      #pragma unroll
      for (int rt = 0; rt < 4; rt++){
        const int row = hh*64 + rt*16 + l15;
        bf16x8 afr[4];
        #pragma unroll
        for (int kb = 0; kb < 4; kb++)
          afr[kb] = *(const bf16x8*)((const char*)Wl + aoff((uint32_t)row, kb*64 + l4*16));
        const int h0 = hh*64 + rt*16 + l4*4;
        const f32x4 bo4 = *(const f32x4*)(bo_c + c*128 + h0);
        #pragma unroll
        for (int ct = 0; ct < 2; ct++){
          f32x4 acc = {0.f,0.f,0.f,0.f};
          #pragma unroll
          for (int kb = 0; kb < 4; kb++) acc = MFMA(afr[kb], bfr[ct][kb], acc);
          f32x4 rr;
          rr.x = __builtin_amdgcn_rcpf(__builtin_amdgcn_exp2f(acc.x + bo4.x) + 1.f);
          rr.y = __builtin_amdgcn_rcpf(__builtin_amdgcn_exp2f(acc.y + bo4.y) + 1.f);
          rr.z = __builtin_amdgcn_rcpf(__builtin_amdgcn_exp2f(acc.z + bo4.z) + 1.f);
          rr.w = __builtin_amdgcn_rcpf(__builtin_amdgcn_exp2f(acc.w + bo4.w) + 1.f);
          out[rt][ct] += rr * d0v[ct];
        }
      }
      if (k + 1 < nc) wrst((k & 1) ? Pb : Qb, Ra);
      if (k + 2 < nc) ldst((const char*)Wt + (size_t)(cbase + k + 2)*32768, Ra);
      __syncthreads();
    }

    // partials via sc1 (write-through to IC; no L2 dirty state)
    #pragma unroll
    for (int rt = 0; rt < 4; rt++){
      const int h0 = hh*64 + rt*16 + l4*4;
      #pragma unroll
      for (int ct = 0; ct < 2; ct++){
        const int b = mi*128 + bq*32 + ct*16 + l15;
        uint64_t* pp = (uint64_t*)&partials[((size_t)ci*1024 + b)*128 + h0];
        union { f32x2 f; uint64_t u; } a0, a1;
        a0.f = (f32x2){ out[rt][ct].x, out[rt][ct].y };
        a1.f = (f32x2){ out[rt][ct].z, out[rt][ct].w };
        __hip_atomic_store(pp,     a0.u, __ATOMIC_RELAXED, __HIP_MEMORY_SCOPE_AGENT);
        __hip_atomic_store(pp + 1, a1.u, __ATOMIC_RELAXED, __HIP_MEMORY_SCOPE_AGENT);
      }
    }
    __syncthreads();                         // drains every wave's vmem (stores acked at IC)
    if (t == 0) bar_arrive(bar, (uint32_t)(2*e + 1), grp);

    // ---- bar1 window: stage next eval's w1/c0/c1 (independent of z) ----
    if (e < 143){
      i32x4 R0[4], R1[4];
      ldst(w1t, R1);
      ldst((const char*)Wt + (size_t)cbase*32768, R0);
      ldst((const char*)Wt + (size_t)(cbase + 1)*32768, Ra);
      wrst(Xb, R1); wrst(Pb, R0);
    }
    if (t == 0) bar_wait(bar, (uint32_t)(2*e + 1));
    __syncthreads();

    // ========== phase B: reduce + RK4 (sc1 reads, regs state) ==========
    if (t < 256){
      float s0 = 0.f, s1 = 0.f;
      #pragma unroll
      for (int sl = 0; sl < 32; sl++){
        union { uint64_t u; f32x2 f; } v;
        v.u = __hip_atomic_load((const uint64_t*)&partials[((size_t)sl*1024 + bB)*128 + hp2],
                                __ATOMIC_RELAXED, __HIP_MEMORY_SCOPE_AGENT);
        s0 += v.f.x; s1 += v.f.y;
      }
      const float k0 = Sb - 2.f*s0, k1 = Sb - 2.f*s1;
      const int st = e & 3;
      float ze0, ze1;
      if (st == 0){      av0 = k0;      av1 = k1;      ze0 = zb0 + C2*k0; ze1 = zb1 + C2*k1; }
      else if (st == 1){ av0 += 2.f*k0; av1 += 2.f*k1; ze0 = zb0 + C2*k0; ze1 = zb1 + C2*k1; }
      else if (st == 2){ av0 += 2.f*k0; av1 += 2.f*k1; ze0 = zb0 + HS*k0; ze1 = zb1 + HS*k1; }
      else {
        zb0 += C6*(av0 + k0); zb1 += C6*(av1 + k1);
        ze0 = zb0; ze1 = zb1;
        if ((e & 15) == 15){
          const int iv = (e >> 4) + 1;
          hT[(size_t)bB*1280 + (size_t)iv*128 + hp2]     = zb0;
          hT[(size_t)bB*1280 + (size_t)iv*128 + hp2 + 1] = zb1;
        }
      }
      __hip_atomic_store((uint32_t*)((char*)zbuf + zbyte), pkbf(ze0, ze1),
                         __ATOMIC_RELAXED, __HIP_MEMORY_SCOPE_AGENT);
    }
    __syncthreads();                         // drains phase-B stores
    if (e < 143){
      if (t == 0){
        bar_arrive(bar, (uint32_t)(2*e + 2), grp);
        bar_wait(bar, (uint32_t)(2*e + 2));
      }
      __syncthreads();
    }
  }
}

// ---------- readout: poses = leaky(hT @ w_r1 + b_r1) @ w_r2 + b_r2 ; z_final copy ----------
__global__ __launch_bounds__(256) void pose_readout(
    const float* __restrict__ hT, const float* __restrict__ w_r1, const float* __restrict__ b_r1,
    const float* __restrict__ w_r2, const float* __restrict__ b_r2,
    float* __restrict__ out_poses, float* __restrict__ out_z)
{
  if (blockIdx.x >= 320){
    const int cb = blockIdx.x - 320;
    const int base = cb*2048 + threadIdx.x*4;
    #pragma unroll
    for (int p = 0; p < 2; p++){
      const int i = base + p*1024;
      const int b = i >> 7, h = i & 127;
      *(f32x4*)(out_z + i) = *(const f32x4*)(hT + (size_t)b*1280 + 1152 + h);
    }
    return;
  }
  __shared__ float htl[128][32];
  __shared__ float al[32][128];
  const int r0 = blockIdx.x * 32;
  const int t = threadIdx.x;
  { const int row = t >> 3, ch = (t & 7)*16;
    #pragma unroll
    for (int j = 0; j < 16; j++)
      htl[ch + j][row] = hT[(size_t)(r0 + row)*128 + ch + j];
  }
  __syncthreads();
  const int j = t & 127, rg = t >> 7;
  float a[16];
  const float bj = b_r1[j];
  #pragma unroll
  for (int r = 0; r < 16; r++) a[r] = bj;
  #pragma unroll 2
  for (int kk = 0; kk < 128; kk++){
    const float wv = w_r1[(size_t)kk*128 + j];
    const float* pr = &htl[kk][rg*16];
    #pragma unroll
    for (int q = 0; q < 4; q++){
      f32x4 v = *(const f32x4*)(pr + q*4);
      a[q*4+0] += v.x*wv; a[q*4+1] += v.y*wv; a[q*4+2] += v.z*wv; a[q*4+3] += v.w*wv;
    }
  }
  #pragma unroll
  for (int r = 0; r < 16; r++){
    float v = a[r];
    al[rg*16 + r][j] = (v > 0.f) ? v : 0.1f*v;
  }
  __syncthreads();
  if (t < 192){
    const int row = t / 6, p = t % 6;
    float s = b_r2[p];
    const float* ar = al[row];
    #pragma unroll 4
    for (int jj = 0; jj < 128; jj++) s += ar[jj] * w_r2[jj*6 + p];
    out_poses[(size_t)(r0 + row)*6 + p] = s;
  }
}

// ---------- host ----------
extern "C" void kernel_launch(void* const* d_in, const int* in_sizes, int n_in,
                              void* d_out, int out_size, void* d_ws, size_t ws_size,
                              hipStream_t stream)
{
  (void)in_sizes; (void)n_in; (void)out_size; (void)ws_size;
  const float* fv    = (const float*)d_in[0];
  const float* fi    = (const float*)d_in[1];
  const float* ts    = (const float*)d_in[2];
  const float* w_red = (const float*)d_in[3];
  const float* b_red = (const float*)d_in[4];
  const float* w_init= (const float*)d_in[5];
  const float* b_init= (const float*)d_in[6];
  const float* w_h1  = (const float*)d_in[7];
  const float* b_h1  = (const float*)d_in[8];
  const float* w_h2  = (const float*)d_in[9];
  const float* b_h2  = (const float*)d_in[10];
  const float* w_out = (const float*)d_in[11];
  const float* b_out = (const float*)d_in[12];
  const float* w_r1  = (const float*)d_in[13];
  const float* b_r1  = (const float*)d_in[14];
  const float* w_r2  = (const float*)d_in[15];
  const float* b_r2  = (const float*)d_in[16];

  char* p = (char*)d_ws;
  auto take = [&](size_t n){ char* r = p; p += (n + 255) & ~(size_t)255; return r; };
  uint32_t* bar   = (uint32_t*)take(4096);                // barrier state (zeroed per call)
  uint16_t* Wt    = (uint16_t*)take((size_t)129*32768);   // [c][h][k] bf16 swz, x 2log2e
  uint16_t* w1t   = (uint16_t*)take(32768);
  uint16_t* w2t   = (uint16_t*)take(32768);
  float* bo_c     = (float*)take((size_t)129*128*4);
  float* d0g      = (float*)take((size_t)129*1024*4);
  float* Sv       = (float*)take(1024*4);
  float* F0       = (float*)take((size_t)1024*128*4);
  float* z_base   = (float*)take((size_t)1024*128*4);
  uint16_t* zbuf  = (uint16_t*)take((size_t)8*32768);
  float* hT       = (float*)take((size_t)1024*10*128*4);
  float* partials = (float*)take((size_t)32*1024*128*4);

  float* out_poses = (float*)d_out;
  float* out_z     = (float*)d_out + 61440;

  const float SC = 2.8853900817779268f;  // 2*log2(e)

  hipMemsetAsync(bar, 0, 4096, stream);
  pose_convT<<<4,   256, 0, stream>>>(w_h1,  w1t, 128,   1,   0,     1.0f);
  pose_convT<<<4,   256, 0, stream>>>(w_h2,  w2t, 128,   1,   0,     1.0f);
  pose_convT<<<260, 256, 0, stream>>>(w_out, Wt,  16512, 129, 32768, SC);
  pose_misc <<<65,  256, 0, stream>>>(b_out, ts, bo_c, d0g);
  pose_fused<<<128, 256, 0, stream>>>(fv, fi, w_red, b_red, F0, d0g);
  pose_init <<<16,  512, 0, stream>>>(F0, ts, w_init, b_init, d0g, z_base, zbuf, hT, Sv);

  pose_persist<<<256, 512, 0, stream>>>(Wt, w1t, w2t, b_h1, b_h2, bo_c, d0g, Sv,
                                        zbuf, partials, z_base, hT, bar);

  pose_readout<<<384, 256, 0, stream>>>(hT, w_r1, b_r1, w_r2, b_r2, out_poses, out_z);
}

// Round 4
// 2849.476 us; speedup vs baseline: 4.9644x; 1.8514x over previous
//
#include <hip/hip_runtime.h>
#include <stdint.h>

typedef float   f32x4 __attribute__((ext_vector_type(4)));
typedef float   f32x2 __attribute__((ext_vector_type(2)));
typedef int     i32x4 __attribute__((ext_vector_type(4)));
typedef int     i32x2 __attribute__((ext_vector_type(2)));
typedef __bf16  bf16x8 __attribute__((ext_vector_type(8)));

#define DEV __device__ __forceinline__

// ---------- helpers ----------
DEV uint16_t f2bf(float f){                       // RNE f32->bf16
  uint32_t u = __float_as_uint(f);
  u += 0x7fffu + ((u >> 16) & 1u);
  return (uint16_t)(u >> 16);
}
DEV uint32_t pkbf(float lo, float hi){            // pack 2 bf16 into u32
  uint32_t r;
  asm("v_cvt_pk_bf16_f32 %0, %1, %2" : "=v"(r) : "v"(lo), "v"(hi));
  return r;
}
// byte offset inside a [row][128 bf16] (256B) tile row with XOR-16B bank swizzle
DEV uint32_t aoff(uint32_t row, uint32_t q){ return (row << 8) + (q ^ ((row & 7u) << 4)); }

DEV f32x4 MFMA(bf16x8 a, bf16x8 b, f32x4 c){
  return __builtin_amdgcn_mfma_f32_16x16x32_bf16(a, b, c, 0, 0, 0);
}

DEV uint64_t ld_ic64(const void* p){
  return __hip_atomic_load((const uint64_t*)p, __ATOMIC_RELAXED, __HIP_MEMORY_SCOPE_AGENT);
}
DEV uint32_t ld_ic32(const void* p){
  return __hip_atomic_load((const uint32_t*)p, __ATOMIC_RELAXED, __HIP_MEMORY_SCOPE_AGENT);
}
DEV void st_ic32(void* p, uint32_t v){
  __hip_atomic_store((uint32_t*)p, v, __ATOMIC_RELAXED, __HIP_MEMORY_SCOPE_AGENT);
}

// ---------- fence-free grid barrier (relaxed atomics only; bar zeroed per call) ----------
DEV void bar_arrive(uint32_t* bar, uint32_t ep, int grp){
  uint32_t a = __hip_atomic_fetch_add(bar + grp*32, 1u, __ATOMIC_RELAXED, __HIP_MEMORY_SCOPE_AGENT);
  if (a == 32u*ep - 1u){
    uint32_t r = __hip_atomic_fetch_add(bar + 256, 1u, __ATOMIC_RELAXED, __HIP_MEMORY_SCOPE_AGENT);
    if (r == 8u*ep - 1u)
      __hip_atomic_store(bar + 288, ep, __ATOMIC_RELAXED, __HIP_MEMORY_SCOPE_AGENT);
  }
}
DEV void bar_wait(uint32_t* bar, uint32_t ep){
  int spins = 0;
  while (__hip_atomic_load(bar + 288, __ATOMIC_RELAXED, __HIP_MEMORY_SCOPE_AGENT) < ep){
    __builtin_amdgcn_s_sleep(1);
    if (++spins > (1 << 17)) break;   // safety escape -> visible wrong result, not a hang
  }
  asm volatile("" ::: "memory");
}

// ---------- weight convert/transpose: dst[c][h][k] bf16, swizzled, scaled ----------
__global__ __launch_bounds__(256) void pose_convT(const float* __restrict__ src,
    uint16_t* __restrict__ dst, int N, int MOD, int CB, float scale)
{
  __shared__ float tile[32][256];
  int bk = blockIdx.x & 3, bn = blockIdx.x >> 2;
  int k0 = bk * 32, n0 = bn * 256;
  int t = threadIdx.x;
  for (int r = 0; r < 32; r++){
    int n = n0 + t;
    tile[r][t] = (n < N) ? src[(size_t)(k0 + r) * N + n] : 0.f;
  }
  __syncthreads();
  int n = n0 + t;
  if (n < N){
    int c = n % MOD, h = n / MOD;
    #pragma unroll
    for (int o = 0; o < 4; o++){
      uint32_t w0 = (uint32_t)f2bf(tile[o*8+0][t]*scale) | ((uint32_t)f2bf(tile[o*8+1][t]*scale) << 16);
      uint32_t w1 = (uint32_t)f2bf(tile[o*8+2][t]*scale) | ((uint32_t)f2bf(tile[o*8+3][t]*scale) << 16);
      uint32_t w2 = (uint32_t)f2bf(tile[o*8+4][t]*scale) | ((uint32_t)f2bf(tile[o*8+5][t]*scale) << 16);
      uint32_t w3 = (uint32_t)f2bf(tile[o*8+6][t]*scale) | ((uint32_t)f2bf(tile[o*8+7][t]*scale) << 16);
      i32x4 val = { (int)w0, (int)w1, (int)w2, (int)w3 };
      uint32_t byte = (uint32_t)c * (uint32_t)CB + aoff((uint32_t)h, (uint32_t)(k0 + o*8) * 2);
      *(i32x4*)((char*)dst + byte) = val;
    }
  }
}

// ---------- bo_c[c][h] = b_out[h*129+c]*SCALE ; d0g[0][b] = ts[b,2]-ts[b,1] ----------
__global__ __launch_bounds__(256) void pose_misc(const float* __restrict__ b_out,
    const float* __restrict__ ts, float* __restrict__ bo_c, float* __restrict__ d0g)
{
  int i = blockIdx.x * 256 + threadIdx.x;
  if (i < 16512){
    int c = i % 129, h = i / 129;
    bo_c[c*128 + h] = b_out[i] * 2.8853900817779268f;
  }
  if (i < 1024) d0g[i] = ts[i*12 + 2] - ts[i*12 + 1];
}

// ---------- fused rows l=0,1 (f32 exact): F0, d0g[1+h][b] ----------
__global__ __launch_bounds__(256) void pose_fused(
    const float* __restrict__ fv, const float* __restrict__ fi,
    const float* __restrict__ w_red, const float* __restrict__ b_red,
    float* __restrict__ F0, float* __restrict__ d0g)
{
  __shared__ float pk[128][16];
  __shared__ float res[16][128];
  const int b0 = blockIdx.x * 8;
  const int t = threadIdx.x;
  const int h = t & 127, sg = t >> 7;
  float acc[8] = {0.f,0.f,0.f,0.f,0.f,0.f,0.f,0.f};
  for (int p = 0; p < 6; p++){
    __syncthreads();
    { const int s  = t >> 4;
      const int ch = (t & 15) * 8;
      const int b  = b0 + (s & 7);
      const int ll = s >> 3;
      const int kb = p*128 + ch;
      const float* src = (kb < 512) ? (fv + ((size_t)b*11 + ll)*512 + kb)
                                    : (fi + ((size_t)b*11 + ll)*256 + (kb - 512));
      float v[8];
      #pragma unroll
      for (int j = 0; j < 8; j++) v[j] = src[j];
      #pragma unroll
      for (int j = 0; j < 8; j++) pk[ch + j][s] = v[j];
    }
    __syncthreads();
    #pragma unroll 4
    for (int kk = 0; kk < 128; kk++){
      const float wv = w_red[(size_t)(p*128 + kk)*128 + h];
      f32x4 v0 = *(const f32x4*)&pk[kk][sg*8];
      f32x4 v1 = *(const f32x4*)&pk[kk][sg*8 + 4];
      acc[0] += v0.x*wv; acc[1] += v0.y*wv; acc[2] += v0.z*wv; acc[3] += v0.w*wv;
      acc[4] += v1.x*wv; acc[5] += v1.y*wv; acc[6] += v1.z*wv; acc[7] += v1.w*wv;
    }
  }
  __syncthreads();
  const float br = b_red[h];
  #pragma unroll
  for (int si = 0; si < 8; si++) res[sg*8 + si][h] = acc[si] + br;
  __syncthreads();
  if (sg == 0){
    #pragma unroll
    for (int si = 0; si < 8; si++){
      const int b = b0 + si;
      const float f0 = res[si][h];
      const float f1 = res[8 + si][h];
      F0[(size_t)b*128 + h] = f0;
      d0g[(size_t)(1 + h)*1024 + b] = f1 - f0;
    }
  }
}

// ---------- z0 = x0 @ w_init + b_init (f32); also S[b] = sum_c d0 ----------
__global__ __launch_bounds__(512) void pose_init(
    const float* __restrict__ F0, const float* __restrict__ ts,
    const float* __restrict__ w_init, const float* __restrict__ b_init,
    const float* __restrict__ d0g,
    float* __restrict__ z_base, uint16_t* __restrict__ zbuf,
    float* __restrict__ hT, float* __restrict__ S)
{
  __shared__ float Ft[128][64];
  const int b0 = blockIdx.x * 64;
  const int t = threadIdx.x;
  { const int b = t >> 3, ch = (t & 7)*16;
    #pragma unroll
    for (int j = 0; j < 16; j++) Ft[ch + j][b] = F0[(size_t)(b0 + b)*128 + ch + j];
  }
  __syncthreads();
  const int h = t & 127, rg = t >> 7;
  float acc[16];
  const float w0 = w_init[h], bi = b_init[h];
  #pragma unroll
  for (int r = 0; r < 16; r++){
    const int b = b0 + rg*16 + r;
    acc[r] = (ts[b*12 + 1] - ts[b*12 + 0]) * w0 + bi;
  }
  #pragma unroll 2
  for (int j = 0; j < 128; j++){
    const float wv = w_init[(j + 1)*128 + h];
    const float* pr = &Ft[j][rg*16];
    #pragma unroll
    for (int q = 0; q < 4; q++){
      f32x4 v = *(const f32x4*)(pr + q*4);
      acc[q*4+0] += v.x*wv; acc[q*4+1] += v.y*wv; acc[q*4+2] += v.z*wv; acc[q*4+3] += v.w*wv;
    }
  }
  #pragma unroll
  for (int r = 0; r < 16; r++){
    const int b = b0 + rg*16 + r;
    const float z = acc[r];
    z_base[(size_t)b*128 + h] = z;
    hT[(size_t)b*1280 + h] = z;
    // zbuf: [team = b>>6][row = b&63][h], 256B rows, XOR-16B swizzle
    uint32_t byte = (uint32_t)(b >> 6) * 16384u + aoff((uint32_t)(b & 63), (uint32_t)h*2);
    *(uint16_t*)((char*)zbuf + byte) = f2bf(z);
  }
  if (t < 64){
    const int b = b0 + t;
    float s = 0.f;
    for (int c = 0; c < 129; c++) s += d0g[(size_t)c*1024 + b];
    S[b] = s;
  }
}

// ---------- persistent: 144 evals; 16 teams x 16 chunks; coalesced IC data plane ----------
__global__ __launch_bounds__(512) void pose_persist(
    const uint16_t* __restrict__ Wt, const uint16_t* __restrict__ w1t,
    const uint16_t* __restrict__ w2t,
    const float* __restrict__ b1, const float* __restrict__ b2,
    const float* __restrict__ bo_c, const float* __restrict__ d0g,
    const float* __restrict__ Sv,
    uint16_t* __restrict__ zbuf, float* __restrict__ partials,
    const float* __restrict__ z_base,
    float* __restrict__ hT, uint32_t* __restrict__ bar)
{
  __shared__ uint16_t Yb[16384];            // w2, resident (32KB)
  __shared__ uint16_t Buf0[16384], Buf1[16384]; // chunk double-buffer / w1+c0 (2x32KB)
  __shared__ uint16_t H1[8192], H2[8192];   // chain outputs, [64 rows][128 k] (2x16KB)
  __shared__ float    ztr[8][64];           // phase-B transpose (2KB)

  const int t   = threadIdx.x;
  const int blk = blockIdx.x;
  const int grp = blk & 7;
  const int mi  = blk >> 4;                 // team (64 batch rows), 16 teams
  const int ci  = (blk & 7)*2 + ((blk >> 3) & 1);  // chunk set, XCD-localized
  const int nc  = (ci == 15) ? 9 : 8;
  const int cbase = ci * 8;
  const int l  = t & 63, w = t >> 6;
  const int hh = w >> 2, bq = w & 3;        // wave tile [64 h][16 b]
  const int l15 = l & 15, l4 = l >> 4;
  const int col16 = bq*16 + l15;            // batch col within team [0,64)
  const int bg = mi*64 + col16;             // global batch for phase-A epilogue

  // phase-B ownership: thread <-> (h = (blk&15)*8 + (t>>6), b = mi*64 + (t&63))
  const int h0B = (blk & 15) * 8;
  const int hB = h0B + (t >> 6), bB = mi*64 + (t & 63);
  const float HS = 0x1.999996p-6f;          // jax f32 hstep
  const float C2 = HS * 0.5f, C6 = HS / 6.f;
  float zb = z_base[(size_t)bB*128 + hB];
  float av = 0.f;
  const float Sb = Sv[bB];
  const char* zsl = (const char*)zbuf + (size_t)mi*16384;

  i32x4 Ra[4];
  auto ldst = [&](const void* g, i32x4* r){
    const i32x4* s = (const i32x4*)g;
    #pragma unroll
    for (int i = 0; i < 4; i++) r[i] = s[t + 512*i];
  };
  auto wrst = [&](uint16_t* lds, const i32x4* r){
    i32x4* d = (i32x4*)lds;
    #pragma unroll
    for (int i = 0; i < 4; i++) d[t + 512*i] = r[i];
  };
  // chain GEMM: D[col=b][k=h_out] = relu(W . B + bias); B-frags in regs
  auto chain_core = [&](const uint16_t* Wl, const bf16x8 (&bfr)[4], const float* bias, uint16_t* Dl){
    #pragma unroll
    for (int rt = 0; rt < 4; rt++){
      const int row = hh*64 + rt*16 + l15;
      bf16x8 afr[4];
      #pragma unroll
      for (int kb = 0; kb < 4; kb++)
        afr[kb] = *(const bf16x8*)((const char*)Wl + aoff((uint32_t)row, kb*64 + l4*16));
      const int h0 = hh*64 + rt*16 + l4*4;
      const f32x4 bias4 = *(const f32x4*)(bias + h0);
      f32x4 acc = {0.f,0.f,0.f,0.f};
      #pragma unroll
      for (int kb = 0; kb < 4; kb++) acc = MFMA(afr[kb], bfr[kb], acc);
      const float r0 = fmaxf(acc.x + bias4.x, 0.f);
      const float r1 = fmaxf(acc.y + bias4.y, 0.f);
      const float r2 = fmaxf(acc.z + bias4.z, 0.f);
      const float r3 = fmaxf(acc.w + bias4.w, 0.f);
      i32x2 pv = { (int)pkbf(r0, r1), (int)pkbf(r2, r3) };
      *(i32x2*)((char*)Dl + aoff((uint32_t)col16, (uint32_t)h0*2)) = pv;
    }
  };
  auto ld_bfr_lds = [&](const uint16_t* Bl, bf16x8 (&bfr)[4]){
    #pragma unroll
    for (int kb = 0; kb < 4; kb++)
      bfr[kb] = *(const bf16x8*)((const char*)Bl + aoff((uint32_t)col16, kb*64 + l4*16));
  };

  // ---- prologue: Buf0=w1, Buf1=c0, Ra=c1, Yb=w2
  { i32x4 R0[4], R1[4], R2[4];
    ldst(w1t, R1); ldst(w2t, R2);
    ldst((const char*)Wt + (size_t)cbase*32768, R0);
    ldst((const char*)Wt + (size_t)(cbase + 1)*32768, Ra);
    wrst(Buf0, R1); wrst(Yb, R2); wrst(Buf1, R0);
  }
  __syncthreads();

  #pragma unroll 1
  for (int e = 0; e < 144; e++){
    // ========== phase A ==========
    // z B-fragments straight from IC
    bf16x8 bz[4];
    #pragma unroll
    for (int kb = 0; kb < 4; kb++){
      const char* a = zsl + aoff((uint32_t)col16, kb*64 + l4*16);
      union { uint64_t q[2]; bf16x8 v; } u;
      u.q[0] = ld_ic64(a);
      u.q[1] = ld_ic64(a + 8);
      bz[kb] = u.v;
    }
    chain_core(Buf0, bz, b1, H1);          // h1 = relu(w1 . z) -> H1
    __syncthreads();
    { bf16x8 bh1[4];
      ld_bfr_lds(H1, bh1);
      chain_core(Yb, bh1, b2, H2);         // h2 = relu(w2 . h1) -> H2
    }
    __syncthreads();
    wrst(Buf0, Ra);                        // c1 -> Buf0 (w1 consumed)

    bf16x8 bfr[4];                         // h2 B-frags, constant over chunks
    ld_bfr_lds(H2, bfr);

    f32x4 out[4];
    const f32x4 Z4 = {0.f,0.f,0.f,0.f};
    #pragma unroll
    for (int rt = 0; rt < 4; rt++) out[rt] = Z4;

    for (int k = 0; k < nc; k++){
      const int c = cbase + k;
      const uint16_t* Wl = (k & 1) ? Buf0 : Buf1;
      if (k + 2 < nc) ldst((const char*)Wt + (size_t)(cbase + k + 2)*32768, Ra);
      const float d0 = d0g[(size_t)c*1024 + bg];
      #pragma unroll
      for (int rt = 0; rt < 4; rt++){
        const int row = hh*64 + rt*16 + l15;
        bf16x8 afr[4];
        #pragma unroll
        for (int kb = 0; kb < 4; kb++)
          afr[kb] = *(const bf16x8*)((const char*)Wl + aoff((uint32_t)row, kb*64 + l4*16));
        const int h0 = hh*64 + rt*16 + l4*4;
        const f32x4 bo4 = *(const f32x4*)(bo_c + c*128 + h0);
        f32x4 acc = {0.f,0.f,0.f,0.f};
        #pragma unroll
        for (int kb = 0; kb < 4; kb++) acc = MFMA(afr[kb], bfr[kb], acc);
        f32x4 rr;
        rr.x = __builtin_amdgcn_rcpf(__builtin_amdgcn_exp2f(acc.x + bo4.x) + 1.f);
        rr.y = __builtin_amdgcn_rcpf(__builtin_amdgcn_exp2f(acc.y + bo4.y) + 1.f);
        rr.z = __builtin_amdgcn_rcpf(__builtin_amdgcn_exp2f(acc.z + bo4.z) + 1.f);
        rr.w = __builtin_amdgcn_rcpf(__builtin_amdgcn_exp2f(acc.w + bo4.w) + 1.f);
        out[rt] += rr * d0;
      }
      __syncthreads();
      if (k + 2 < nc) wrst((k & 1) ? Buf0 : Buf1, Ra);
    }

    // partials[ci][h][b] via IC, lanes b-consecutive (coalesced 4B stores)
    #pragma unroll
    for (int rt = 0; rt < 4; rt++){
      const int h0 = hh*64 + rt*16 + l4*4;
      #pragma unroll
      for (int j = 0; j < 4; j++){
        union { float f; uint32_t u; } v; v.f = out[rt][j];
        st_ic32(&partials[((size_t)ci*128 + h0 + j)*1024 + bg], v.u);
      }
    }
    __syncthreads();                       // drains all vmem (stores acked)
    if (t == 0) bar_arrive(bar, (uint32_t)(2*e + 1), grp);

    // ---- bar1 window: stage next eval's w1->Buf0, c0->Buf1, c1->Ra ----
    if (e < 143){
      i32x4 R0[4], R1[4];
      ldst(w1t, R1);
      ldst((const char*)Wt + (size_t)cbase*32768, R0);
      ldst((const char*)Wt + (size_t)(cbase + 1)*32768, Ra);
      wrst(Buf0, R1); wrst(Buf1, R0);
    }
    if (t == 0) bar_wait(bar, (uint32_t)(2*e + 1));
    __syncthreads();

    // ========== phase B: reduce + RK4 (all 512 threads, 1 elem each) ==========
    {
      float s = 0.f;
      #pragma unroll
      for (int sl = 0; sl < 16; sl++){
        union { uint32_t u; float f; } v;
        v.u = ld_ic32(&partials[((size_t)sl*128 + hB)*1024 + bB]);
        s += v.f;
      }
      const float kk = Sb - 2.f*s;
      const int st = e & 3;
      float ze;
      if (st == 0){      av = kk;        ze = zb + C2*kk; }
      else if (st == 1){ av += 2.f*kk;   ze = zb + C2*kk; }
      else if (st == 2){ av += 2.f*kk;   ze = zb + HS*kk; }
      else {             zb += C6*(av + kk); ze = zb; }
      ztr[t >> 6][t & 63] = ze;
    }
    __syncthreads();
    if (t < 256){
      const int r = t >> 2, pp = t & 3;    // row = b within team, h-pair
      const uint32_t pv = pkbf(ztr[2*pp][r], ztr[2*pp + 1][r]);
      st_ic32((char*)zbuf + (size_t)mi*16384 + aoff((uint32_t)r, (uint32_t)(h0B + 2*pp)*2), pv);
    }
    if ((e & 15) == 15){
      const int r = t >> 3, hl = t & 7;    // coalesced hT write via ztr
      hT[(size_t)(mi*64 + r)*1280 + (size_t)((e >> 4) + 1)*128 + h0B + hl] = ztr[hl][r];
    }
    __syncthreads();                       // drains phase-B stores
    if (e < 143){
      if (t == 0){
        bar_arrive(bar, (uint32_t)(2*e + 2), grp);
        bar_wait(bar, (uint32_t)(2*e + 2));
      }
      __syncthreads();
    }
  }
}

// ---------- readout: poses = leaky(hT @ w_r1 + b_r1) @ w_r2 + b_r2 ; z_final copy ----------
__global__ __launch_bounds__(256) void pose_readout(
    const float* __restrict__ hT, const float* __restrict__ w_r1, const float* __restrict__ b_r1,
    const float* __restrict__ w_r2, const float* __restrict__ b_r2,
    float* __restrict__ out_poses, float* __restrict__ out_z)
{
  if (blockIdx.x >= 320){
    const int cb = blockIdx.x - 320;
    const int base = cb*2048 + threadIdx.x*4;
    #pragma unroll
    for (int p = 0; p < 2; p++){
      const int i = base + p*1024;
      const int b = i >> 7, h = i & 127;
      *(f32x4*)(out_z + i) = *(const f32x4*)(hT + (size_t)b*1280 + 1152 + h);
    }
    return;
  }
  __shared__ float htl[128][32];
  __shared__ float al[32][128];
  const int r0 = blockIdx.x * 32;
  const int t = threadIdx.x;
  { const int row = t >> 3, ch = (t & 7)*16;
    #pragma unroll
    for (int j = 0; j < 16; j++)
      htl[ch + j][row] = hT[(size_t)(r0 + row)*128 + ch + j];
  }
  __syncthreads();
  const int j = t & 127, rg = t >> 7;
  float a[16];
  const float bj = b_r1[j];
  #pragma unroll
  for (int r = 0; r < 16; r++) a[r] = bj;
  #pragma unroll 2
  for (int kk = 0; kk < 128; kk++){
    const float wv = w_r1[(size_t)kk*128 + j];
    const float* pr = &htl[kk][rg*16];
    #pragma unroll
    for (int q = 0; q < 4; q++){
      f32x4 v = *(const f32x4*)(pr + q*4);
      a[q*4+0] += v.x*wv; a[q*4+1] += v.y*wv; a[q*4+2] += v.z*wv; a[q*4+3] += v.w*wv;
    }
  }
  #pragma unroll
  for (int r = 0; r < 16; r++){
    float v = a[r];
    al[rg*16 + r][j] = (v > 0.f) ? v : 0.1f*v;
  }
  __syncthreads();
  if (t < 192){
    const int row = t / 6, p = t % 6;
    float s = b_r2[p];
    const float* ar = al[row];
    #pragma unroll 4
    for (int jj = 0; jj < 128; jj++) s += ar[jj] * w_r2[jj*6 + p];
    out_poses[(size_t)(r0 + row)*6 + p] = s;
  }
}

// ---------- host ----------
extern "C" void kernel_launch(void* const* d_in, const int* in_sizes, int n_in,
                              void* d_out, int out_size, void* d_ws, size_t ws_size,
                              hipStream_t stream)
{
  (void)in_sizes; (void)n_in; (void)out_size; (void)ws_size;
  const float* fv    = (const float*)d_in[0];
  const float* fi    = (const float*)d_in[1];
  const float* ts    = (const float*)d_in[2];
  const float* w_red = (const float*)d_in[3];
  const float* b_red = (const float*)d_in[4];
  const float* w_init= (const float*)d_in[5];
  const float* b_init= (const float*)d_in[6];
  const float* w_h1  = (const float*)d_in[7];
  const float* b_h1  = (const float*)d_in[8];
  const float* w_h2  = (const float*)d_in[9];
  const float* b_h2  = (const float*)d_in[10];
  const float* w_out = (const float*)d_in[11];
  const float* b_out = (const float*)d_in[12];
  const float* w_r1  = (const float*)d_in[13];
  const float* b_r1  = (const float*)d_in[14];
  const float* w_r2  = (const float*)d_in[15];
  const float* b_r2  = (const float*)d_in[16];

  char* p = (char*)d_ws;
  auto take = [&](size_t n){ char* r = p; p += (n + 255) & ~(size_t)255; return r; };
  uint32_t* bar   = (uint32_t*)take(4096);                // barrier state (zeroed per call)
  uint16_t* Wt    = (uint16_t*)take((size_t)129*32768);   // [c][h][k] bf16 swz, x 2log2e
  uint16_t* w1t   = (uint16_t*)take(32768);
  uint16_t* w2t   = (uint16_t*)take(32768);
  float* bo_c     = (float*)take((size_t)129*128*4);
  float* d0g      = (float*)take((size_t)129*1024*4);
  float* Sv       = (float*)take(1024*4);
  float* F0       = (float*)take((size_t)1024*128*4);
  float* z_base   = (float*)take((size_t)1024*128*4);
  uint16_t* zbuf  = (uint16_t*)take((size_t)16*16384);    // [team][row b][h] bf16 swz
  float* hT       = (float*)take((size_t)1024*10*128*4);
  float* partials = (float*)take((size_t)16*128*1024*4);  // [ci][h][b]

  float* out_poses = (float*)d_out;
  float* out_z     = (float*)d_out + 61440;

  const float SC = 2.8853900817779268f;  // 2*log2(e)

  hipMemsetAsync(bar, 0, 4096, stream);
  pose_convT<<<4,   256, 0, stream>>>(w_h1,  w1t, 128,   1,   0,     1.0f);
  pose_convT<<<4,   256, 0, stream>>>(w_h2,  w2t, 128,   1,   0,     1.0f);
  pose_convT<<<260, 256, 0, stream>>>(w_out, Wt,  16512, 129, 32768, SC);
  pose_misc <<<65,  256, 0, stream>>>(b_out, ts, bo_c, d0g);
  pose_fused<<<128, 256, 0, stream>>>(fv, fi, w_red, b_red, F0, d0g);
  pose_init <<<16,  512, 0, stream>>>(F0, ts, w_init, b_init, d0g, z_base, zbuf, hT, Sv);

  pose_persist<<<256, 512, 0, stream>>>(Wt, w1t, w2t, b_h1, b_h2, bo_c, d0g, Sv,
                                        zbuf, partials, z_base, hT, bar);

  pose_readout<<<384, 256, 0, stream>>>(hT, w_r1, b_r1, w_r2, b_r2, out_poses, out_z);
}